// Round 8
// baseline (185.887 us; speedup 1.0000x reference)
//
#include <hip/hip_runtime.h>

#define N_NODES 50000
#define N_EDGES 640000
#define D 128          // D_IN == D_OUT
#define NB 8           // num bases
#define CH 8           // src chunks; y-chunk = 6250*256B = 1.6 MB -> fits 4MB XCD L2
#define CSZ 6250       // srcs per chunk (8*6250 = 50000 exactly)
#define PADC 12        // slots per (dst,chunk); Poisson(1.6), P(>12)~1e-8
#define NSTRIP 3125    // 50000/16 M-strips for gemm
#define GRID_G 1024    // gemm blocks

typedef _Float16 half_t;
typedef __attribute__((ext_vector_type(8))) _Float16 half8;
typedef __attribute__((ext_vector_type(4))) float f32x4;
typedef unsigned short u16;

// ---- k1: zero (dst,chunk) counters + build Wt/Rt (fp16, transposed [n][k]) ----
__global__ __launch_bounds__(256)
void init_kernel(const float* __restrict__ bases,
                 const float* __restrict__ comp,
                 const float* __restrict__ root,
                 half_t* __restrict__ Wt,
                 half_t* __restrict__ Rt,
                 int* __restrict__ cnt) {
    int i = blockIdx.x * 256 + threadIdx.x;
    if (i < N_NODES * CH) cnt[i] = 0;
    if (i < D * D) {
        int ii = i >> 7, o = i & 127;
        float acc = 0.f;
#pragma unroll
        for (int b = 0; b < NB; ++b)
            acc += comp[b] * bases[((size_t)b * D + ii) * D + o];
        Wt[o * D + ii] = (half_t)acc;
        Rt[o * D + ii] = (half_t)root[i];
    }
}

// ---- k2: y(half) = x@W ; out(f32) = x@root + bias (B-resident waves, R7) ----
__global__ __launch_bounds__(256, 4)
void gemm_kernel(const float* __restrict__ x,
                 const half_t* __restrict__ Wt,   // [n][k]
                 const half_t* __restrict__ Rt,   // [n][k]
                 const float* __restrict__ bias,
                 half_t* __restrict__ y,
                 float* __restrict__ out) {
    const int tid  = threadIdx.x;
    const int wave = tid >> 6;
    const int lane = tid & 63;
    const int m    = lane & 15;
    const int quad = lane >> 4;
    const int gw   = blockIdx.x * 4 + wave;
    const int q    = gw & 3;                 // col quarter: nt = 2q, 2q+1
    const int s0   = gw >> 2;                // starting M-strip

    half8 bw[2][4], br[2][4];
    float bb[2];
#pragma unroll
    for (int t = 0; t < 2; ++t) {
        const int nt = 2 * q + t;
        const half_t* wp = Wt + (nt * 16 + m) * D + quad * 8;
        const half_t* rp = Rt + (nt * 16 + m) * D + quad * 8;
#pragma unroll
        for (int kk = 0; kk < 4; ++kk) {
            bw[t][kk] = *(const half8*)(wp + kk * 32);
            br[t][kk] = *(const half8*)(rp + kk * 32);
        }
        bb[t] = bias[nt * 16 + m];
    }

    const float4* x4 = (const float4*)x;
    for (int s = s0; s < NSTRIP; s += GRID_G) {
        size_t ab = (size_t)(s * 16 + m) * 32 + quad * 2;
        half8 a[4];
#pragma unroll
        for (int kk = 0; kk < 4; ++kk) {
            float4 v0 = x4[ab + kk * 8];
            float4 v1 = x4[ab + kk * 8 + 1];
            half8 h;
            h[0] = (half_t)v0.x; h[1] = (half_t)v0.y; h[2] = (half_t)v0.z; h[3] = (half_t)v0.w;
            h[4] = (half_t)v1.x; h[5] = (half_t)v1.y; h[6] = (half_t)v1.z; h[7] = (half_t)v1.w;
            a[kk] = h;
        }

        f32x4 accW[2], accR[2];
#pragma unroll
        for (int t = 0; t < 2; ++t) {
            accW[t] = (f32x4){0.f, 0.f, 0.f, 0.f};
            accR[t] = (f32x4){0.f, 0.f, 0.f, 0.f};
        }
#pragma unroll
        for (int t = 0; t < 2; ++t)
#pragma unroll
            for (int kk = 0; kk < 4; ++kk) {
                accW[t] = __builtin_amdgcn_mfma_f32_16x16x32_f16(a[kk], bw[t][kk], accW[t], 0, 0, 0);
                accR[t] = __builtin_amdgcn_mfma_f32_16x16x32_f16(a[kk], br[t][kk], accR[t], 0, 0, 0);
            }

#pragma unroll
        for (int t = 0; t < 2; ++t) {
            int col = (2 * q + t) * 16 + m;
#pragma unroll
            for (int r = 0; r < 4; ++r) {
                int row = s * 16 + quad * 4 + r;
                y[(size_t)row * D + col]   = (half_t)accW[t][r];
                out[(size_t)row * D + col] = accR[t][r] + bb[t];
            }
        }
    }
}

// ---- k3: bucket edges by (dst, src_chunk); ushort src indices ----
__global__ __launch_bounds__(256)
void bucket_kernel(const int* __restrict__ eidx,
                   const half_t* __restrict__ y,
                   float* __restrict__ out,
                   int* __restrict__ cnt,
                   u16* __restrict__ bucket) {
    int e = blockIdx.x * 256 + threadIdx.x;
    if (e >= N_EDGES) return;
    int src = eidx[e];
    int dst = eidx[N_EDGES + e];
    int ch  = src / CSZ;
    int cell = dst * CH + ch;
    int pos = atomicAdd(&cnt[cell], 1);
    if (pos < PADC) {
        bucket[(size_t)cell * PADC + pos] = (u16)src;
    } else {   // P ~ 1e-8 per cell; correct fallback (y/out already written by gemm)
        const half_t* yr = y + (size_t)src * D;
        float* op = out + (size_t)dst * D;
        for (int q = 0; q < D; ++q) atomicAdd(op + q, (float)yr[q]);
    }
}

// ---- k4: gather, 16 lanes per node; chunks walked in order for L2 locality ----
__global__ __launch_bounds__(256)
void gather_kernel(const int* __restrict__ cnt,
                   const u16* __restrict__ bucket,
                   const half_t* __restrict__ y,
                   float* __restrict__ out) {
    int node = blockIdx.x * 16 + (threadIdx.x >> 4);
    int q = threadIdx.x & 15;
    if (node >= N_NODES) return;

    const int4* cp = (const int4*)(cnt + node * CH);   // 32-B aligned
    int4 ca = cp[0], cb = cp[1];
    int cArr[8] = {ca.x, ca.y, ca.z, ca.w, cb.x, cb.y, cb.z, cb.w};
    const u16* nb = bucket + (size_t)node * CH * PADC;

    float acc[8] = {0.f, 0.f, 0.f, 0.f, 0.f, 0.f, 0.f, 0.f};
#pragma unroll
    for (int ch = 0; ch < CH; ++ch) {
        int c = cArr[ch];
        if (c > PADC) c = PADC;
        const u16* b = nb + ch * PADC;
        int i = 0;
        for (; i + 4 <= c; i += 4) {     // P(c>=4 | lambda=1.6) ~ 8%
            int s0 = b[i], s1 = b[i + 1], s2 = b[i + 2], s3 = b[i + 3];
            half8 v0 = *(const half8*)(y + (size_t)s0 * D + q * 8);
            half8 v1 = *(const half8*)(y + (size_t)s1 * D + q * 8);
            half8 v2 = *(const half8*)(y + (size_t)s2 * D + q * 8);
            half8 v3 = *(const half8*)(y + (size_t)s3 * D + q * 8);
#pragma unroll
            for (int j = 0; j < 8; ++j)
                acc[j] += ((float)v0[j] + (float)v1[j]) + ((float)v2[j] + (float)v3[j]);
        }
        for (; i < c; ++i) {
            int s = b[i];
            half8 v = *(const half8*)(y + (size_t)s * D + q * 8);
#pragma unroll
            for (int j = 0; j < 8; ++j) acc[j] += (float)v[j];
        }
    }

    float4* op = (float4*)(out + (size_t)node * D + q * 8);
    float4 o0 = op[0], o1 = op[1];
    o0.x += acc[0]; o0.y += acc[1]; o0.z += acc[2]; o0.w += acc[3];
    o1.x += acc[4]; o1.y += acc[5]; o1.z += acc[6]; o1.w += acc[7];
    op[0] = o0; op[1] = o1;
}

extern "C" void kernel_launch(void* const* d_in, const int* in_sizes, int n_in,
                              void* d_out, int out_size, void* d_ws, size_t ws_size,
                              hipStream_t stream) {
    const float* x     = (const float*)d_in[0];
    const int*   eidx  = (const int*)d_in[1];
    const float* bases = (const float*)d_in[2];
    const float* comp  = (const float*)d_in[3];
    const float* root  = (const float*)d_in[4];
    const float* bias  = (const float*)d_in[5];
    float* out = (float*)d_out;

    char* ws = (char*)d_ws;
    half_t* y      = (half_t*)ws;                      // 12,800,000 B
    half_t* Wt     = (half_t*)(ws + 12800000);         //     32,768 B
    half_t* Rt     = (half_t*)(ws + 12832768);         //     32,768 B
    int*    cnt    = (int*)   (ws + 12865536);         //  1,600,000 B (50K x 8)
    u16*    bucket = (u16*)   (ws + 14465536);         //  9,600,000 B (50K x 8 x 12)

    init_kernel<<<(N_NODES * CH + 255) / 256, 256, 0, stream>>>(
        bases, comp, root, Wt, Rt, cnt);
    gemm_kernel<<<GRID_G, 256, 0, stream>>>(
        x, Wt, Rt, bias, y, out);
    bucket_kernel<<<(N_EDGES + 255) / 256, 256, 0, stream>>>(
        eidx, y, out, cnt, bucket);
    gather_kernel<<<(N_NODES + 15) / 16, 256, 0, stream>>>(
        cnt, bucket, y, out);
}